// Round 12
// baseline (3800.163 us; speedup 1.0000x reference)
//
#include <hip/hip_runtime.h>
#include <math.h>

#define NN   16384      // total nodes
#define NE   262144     // edges (no self loops)
#define NB   64         // graphs
#define SEQT 256        // nodes per graph (= seq len)
#define DEP  64
#define DOUT 256        // = HID
#define G3   768        // 3*HID
#define GK   256        // GEMM K (always 256 here)
#define ECAP 32         // GCN edges staged per chunk

typedef _Float16 h2_t   __attribute__((ext_vector_type(2)));
typedef _Float16 f16x4  __attribute__((ext_vector_type(4)));
typedef _Float16 f16x8  __attribute__((ext_vector_type(8)));
typedef float    f32x4  __attribute__((ext_vector_type(4)));

static __device__ __forceinline__ h2_t pk(float a, float b) {
    return (h2_t)__builtin_amdgcn_cvt_pkrtz(a, b);
}

static __device__ __forceinline__ float fast_sigmoid(float v) {
    return __builtin_amdgcn_rcpf(1.f + __expf(-v));
}
static __device__ __forceinline__ float fast_tanh(float v) {
    return 1.f - 2.f * __builtin_amdgcn_rcpf(1.f + __expf(2.f * v));
}

// barrier with LDS-only drain (no vmcnt: in-flight global loads/stores cross)
static __device__ __forceinline__ void bar_lds() {
    asm volatile("s_waitcnt lgkmcnt(0)\n\ts_barrier" ::: "memory");
}

// ---------------------------------------------------------------------------
// degree / CSR build (deg zero-initialized by memset; holds RAW in-degree)
// ---------------------------------------------------------------------------
__global__ void k_count(const int* __restrict__ ei, int* deg) {
    int e = blockIdx.x * 256 + threadIdx.x;
    if (e < NE) atomicAdd(&deg[ei[NE + e]], 1);   // col = dst
}

__global__ __launch_bounds__(1024) void k_scan_offs(const int* __restrict__ deg,
                                                    int* __restrict__ offs,
                                                    float* __restrict__ dinv) {
    __shared__ int lds[1024];
    const int tid = threadIdx.x;
    const int v0 = tid * 16;
    int loc[16];
    int s = 0;
#pragma unroll
    for (int i = 0; i < 16; ++i) {
        int d = deg[v0 + i];                      // raw in-edges
        loc[i] = s;
        s += d;
        dinv[v0 + i] = rsqrtf((float)(d + 1));    // +1 self loop
    }
    lds[tid] = s;
    __syncthreads();
    for (int off = 1; off < 1024; off <<= 1) {
        int x = (tid >= off) ? lds[tid - off] : 0;
        __syncthreads();
        lds[tid] += x;
        __syncthreads();
    }
    int base = lds[tid] - s;                      // exclusive prefix of this thread
#pragma unroll
    for (int i = 0; i < 16; ++i) offs[v0 + i] = base + loc[i];
}

__global__ void k_fill(const int* __restrict__ ei, const int* __restrict__ offs,
                       int* cursor, int* __restrict__ eidx) {
    int e = blockIdx.x * 256 + threadIdx.x;
    if (e < NE) {
        int c = ei[NE + e];
        int pos = offs[c] + atomicAdd(&cursor[c], 1);
        eidx[pos] = e;
    }
}

__global__ void k_bself(const float* __restrict__ WB, float* Bself) {
    int f = threadIdx.x;                          // 256 threads
    float s = 0.f;
#pragma unroll
    for (int d = 0; d < DEP; ++d) s += WB[f * DEP + d];
    Bself[f] = s;
}

// ---------------------------------------------------------------------------
// one fused fp32->f16 conversion over all 5 regions
// ---------------------------------------------------------------------------
__global__ void k_cvt_all(const float* __restrict__ x,  const float* __restrict__ wa,
                          const float* __restrict__ w0, const float* __restrict__ w1,
                          const float* __restrict__ w2,
                          _Float16* __restrict__ xo,  _Float16* __restrict__ wao,
                          _Float16* __restrict__ w0o, _Float16* __restrict__ w1o,
                          _Float16* __restrict__ w2o) {
    size_t i = ((size_t)blockIdx.x * 256 + threadIdx.x) * 4;
    const size_t B0 = 4194304, B1 = B0 + 65536, B2 = B1 + 196608, B3 = B2 + 196608;
    const float* in; _Float16* out; size_t off;
    if      (i < B0) { in = x;  out = xo;  off = i; }
    else if (i < B1) { in = wa; out = wao; off = i - B0; }
    else if (i < B2) { in = w0; out = w0o; off = i - B1; }
    else if (i < B3) { in = w1; out = w1o; off = i - B2; }
    else             { in = w2; out = w2o; off = i - B3; }
    float4 v = *(const float4*)(in + off);
    *(h2_t*)(out + off)     = pk(v.x, v.y);
    *(h2_t*)(out + off + 2) = pk(v.z, v.w);
}

// ---------------------------------------------------------------------------
// MFMA f16 GEMM: C[M,N] = A16[M,256] @ B16[N,256]^T (+ bias), fp32 out.
// ---------------------------------------------------------------------------
__global__ __launch_bounds__(256) void k_gemm16(const _Float16* __restrict__ A16,
                                                const _Float16* __restrict__ B16,
                                                const float* __restrict__ bias,
                                                float* __restrict__ C,
                                                int M, int N) {
    const int tid  = threadIdx.x;
    const int lane = tid & 63;
    const int wv   = tid >> 6;
    const int m0   = blockIdx.x * 128 + wv * 32;
    const int n0   = blockIdx.y * 128;
    const int ml   = lane & 15;
    const int quad = lane >> 4;

    const _Float16* ap0 = A16 + (size_t)(m0 + ml) * GK + quad * 8;
    const _Float16* ap1 = ap0 + (size_t)16 * GK;
    const _Float16* bp0 = B16 + (size_t)(n0 + ml) * GK + quad * 8;

    f32x4 acc[2][8];
#pragma unroll
    for (int i = 0; i < 2; ++i)
#pragma unroll
        for (int j = 0; j < 8; ++j) acc[i][j] = (f32x4){0.f, 0.f, 0.f, 0.f};

#pragma unroll 2
    for (int k0 = 0; k0 < GK; k0 += 32) {
        f16x8 a0 = *(const f16x8*)(ap0 + k0);
        f16x8 a1 = *(const f16x8*)(ap1 + k0);
#pragma unroll
        for (int nf = 0; nf < 8; ++nf) {
            f16x8 bf = *(const f16x8*)(bp0 + (size_t)nf * 16 * GK + k0);
            acc[0][nf] = __builtin_amdgcn_mfma_f32_16x16x32_f16(a0, bf, acc[0][nf], 0, 0, 0);
            acc[1][nf] = __builtin_amdgcn_mfma_f32_16x16x32_f16(a1, bf, acc[1][nf], 0, 0, 0);
        }
    }

#pragma unroll
    for (int mf = 0; mf < 2; ++mf)
#pragma unroll
        for (int nf = 0; nf < 8; ++nf) {
            const int col = n0 + nf * 16 + ml;
            const float bv = bias ? bias[col] : 0.f;
#pragma unroll
            for (int r = 0; r < 4; ++r) {
                const int row = m0 + mf * 16 + quad * 4 + r;
                C[(size_t)row * N + col] = acc[mf][nf][r] + bv;
            }
        }
}

// ---------------------------------------------------------------------------
// GCN gather v2: chunked LDS staging, fast_tanh.
// ---------------------------------------------------------------------------
__global__ __launch_bounds__(256) void k_gcn(const float* __restrict__ Ax,
                                             const float* __restrict__ WB,
                                             const float* __restrict__ edge_attr,
                                             const int* __restrict__ ei,
                                             const int* __restrict__ eidx,
                                             const int* __restrict__ offs,
                                             const int* __restrict__ deg,
                                             const float* __restrict__ dinv,
                                             const float* __restrict__ Bself,
                                             const float* __restrict__ gcn_bias,
                                             _Float16* __restrict__ node16) {
    const int v = blockIdx.x;
    const int f = threadIdx.x;

    float wb[64];
#pragma unroll
    for (int d4 = 0; d4 < 16; ++d4) {
        float4 t = *(const float4*)&WB[f * DEP + d4 * 4];
        wb[d4 * 4 + 0] = t.x; wb[d4 * 4 + 1] = t.y;
        wb[d4 * 4 + 2] = t.z; wb[d4 * 4 + 3] = t.w;
    }

    __shared__ float ea_s[ECAP * 64];
    __shared__ int   es_s[ECAP];
    __shared__ int   src_s[ECAP];
    __shared__ float nrm_s[ECAP];

    const int   base = offs[v];
    const int   cnt  = deg[v];                   // raw in-edges
    const float dv   = dinv[v];
    float acc = 0.f;

    for (int c0 = 0; c0 < cnt; c0 += ECAP) {
        const int n = min(ECAP, cnt - c0);
        if (f < n) {
            int e = eidx[base + c0 + f];
            es_s[f] = e;
            int s = ei[e];
            src_s[f] = s;
            nrm_s[f] = dinv[s] * dv;
        }
        __syncthreads();
        for (int idx = f; idx < n * 64; idx += 256) {
            int el = idx >> 6, d = idx & 63;
            ea_s[idx] = edge_attr[(size_t)es_s[el] * DEP + d];
        }
        __syncthreads();
        for (int i = 0; i < n; ++i) {
            float ax = Ax[(size_t)src_s[i] * DOUT + f];   // issued early
            float be = 0.f;
#pragma unroll
            for (int d = 0; d < 64; ++d) be = fmaf(wb[d], ea_s[i * 64 + d], be);
            acc = fmaf(nrm_s[i], fast_tanh(ax * be), acc);
        }
        __syncthreads();                          // before chunk overwrite
    }
    // self loop: norm = dinv^2, Be = rowsum(WB)
    acc += dv * dv * fast_tanh(Ax[(size_t)v * DOUT + f] * Bself[f]);
    float nv = fast_tanh(acc / (float)(cnt + 1) + gcn_bias[f]);
    node16[(size_t)v * DOUT + f] = (_Float16)nv;
}

// ---------------------------------------------------------------------------
// GRU scan v9 (in-register gate): 512-thr WG (8 waves = 2/SIMD) per graph.
// Broadcast-B => ALL 16 MFMA columns are identical, so every lane holds the
// matvec for its quad's rows.  Wave wv's six A row-blocks are the r/z/n gate
// rows of j in [32wv,32wv+32): {2wv,2wv+1, 16+2wv,17+2wv, 32+2wv,33+2wv}.
// After the MFMAs each lane has ghr/ghz/ghn for its 8 j-values in C-regs:
// the gate computes fully in-lane (16x m-redundant, zero exchange), h_old
// is per-lane fp32, and only the f16 h-publish needs the single barrier.
// Deleted vs R9: ghL round-trip, one barrier, 4-wave gate serialization.
// layer==2 fuses pooling+linear+softmax and skips the y16 store.
// ---------------------------------------------------------------------------
__global__ __launch_bounds__(512, 2) void k_gru_scan(const float* __restrict__ xp,
                                                     const float* __restrict__ w_hh,
                                                     const float* __restrict__ b_hh,
                                                     _Float16* __restrict__ y16,
                                                     float* __restrict__ hT_all,
                                                     int layer,
                                                     const float* __restrict__ lin_W,
                                                     const float* __restrict__ lin_b,
                                                     float* __restrict__ out) {
    const int tid  = threadIdx.x;
    const int b    = blockIdx.x;                 // graph
    const int lane = tid & 63;
    const int wv   = tid >> 6;                   // wave 0..7
    const int m    = lane & 15;                  // A-frag row within 16
    const int quad = lane >> 4;                  // 0..3 (k-subgroup)
    const int j0   = wv * 32;                    // this wave's gate rows

    // row-block map: rb 0,1 -> r-gate; 2,3 -> z-gate; 4,5 -> n-gate
    int rbmap[6];
#pragma unroll
    for (int g = 0; g < 3; ++g) {
        rbmap[2 * g]     = g * 16 + 2 * wv;
        rbmap[2 * g + 1] = g * 16 + 2 * wv + 1;
    }

    // --- weights -> A-fragments (one-time global read, fp32 -> f16) ---
    f16x8 A[6][8];
#pragma unroll
    for (int rb = 0; rb < 6; ++rb) {
        const int row = rbmap[rb] * 16 + m;
#pragma unroll
        for (int kt = 0; kt < 8; ++kt) {
            const float* wp = w_hh + (size_t)row * 256 + kt * 32 + quad * 8;
            float4 a0 = *(const float4*)wp;
            float4 a1 = *(const float4*)(wp + 4);
            union { f16x8 v; h2_t h[4]; } u;
            u.h[0] = pk(a0.x, a0.y); u.h[1] = pk(a0.z, a0.w);
            u.h[2] = pk(a1.x, a1.y); u.h[3] = pk(a1.z, a1.w);
            A[rb][kt] = u.v;
        }
    }

    // biases for this lane's 8 j-values (j = j0 + k*16 + quad*4 + r)
    float4 bhr4[2], bhz4[2], bhn4[2];
#pragma unroll
    for (int k = 0; k < 2; ++k) {
        const int jb = j0 + k * 16 + quad * 4;
        bhr4[k] = *(const float4*)&b_hh[jb];
        bhz4[k] = *(const float4*)&b_hh[256 + jb];
        bhn4[k] = *(const float4*)&b_hh[512 + jb];
    }

    __shared__ _Float16 h16[2][256];             // h(t) f16, double-buffered
    __shared__ float    pool[1280];              // layer-2 epilogue only
    __shared__ float    red[512];
    float h_old[8];
#pragma unroll
    for (int i = 0; i < 8; ++i) h_old[i] = 0.f;
    if (tid < 256) h16[0][tid] = (_Float16)0.f;
    __syncthreads();

    const float* xpb  = xp  + (size_t)b * SEQT * G3;
    _Float16*    yb16 = y16 + (size_t)b * SEQT * DOUT;

    float mx[8], sm[8];                          // layer-2 pooling accum
#pragma unroll
    for (int i = 0; i < 8; ++i) { mx[i] = -1e30f; sm[i] = 0.f; }

    for (int t = 0; t < SEQT; ++t) {
        // prefetch this step's xp for the lane's 8 js (overlaps MFMA)
        const float* xpt = xpb + (size_t)t * G3;
        float4 xr4[2], xz4[2], xn4[2];
#pragma unroll
        for (int k = 0; k < 2; ++k) {
            const int jb = j0 + k * 16 + quad * 4;
            xr4[k] = *(const float4*)(xpt + jb);
            xz4[k] = *(const float4*)(xpt + 256 + jb);
            xn4[k] = *(const float4*)(xpt + 512 + jb);
        }

        // k-outer MFMA: one B-frag per kt feeds 6 independent chains
        const _Float16* hcur = h16[t & 1];
        f32x4 C[6];
#pragma unroll
        for (int rb = 0; rb < 6; ++rb) C[rb] = (f32x4){0.f, 0.f, 0.f, 0.f};

        union { f16x8 v; float4 f; } Bk, Bn;
        Bk.f = *(const float4*)&hcur[quad * 8];
#pragma unroll
        for (int kt = 0; kt < 8; ++kt) {
            if (kt < 7) Bn.f = *(const float4*)&hcur[(kt + 1) * 32 + quad * 8];
#pragma unroll
            for (int rb = 0; rb < 6; ++rb)
                C[rb] = __builtin_amdgcn_mfma_f32_16x16x32_f16(A[rb][kt], Bk.v, C[rb], 0, 0, 0);
            Bk.v = Bn.v;
        }

        // in-register gate for the lane's 8 js (identical across m lanes)
        f16x4 ph[2];
        float hn4[2][4];
#pragma unroll
        for (int k = 0; k < 2; ++k) {
#pragma unroll
            for (int r = 0; r < 4; ++r) {
                float ghr = C[k][r]     + bhr4[k][r];
                float ghz = C[2 + k][r] + bhz4[k][r];
                float ghn = C[4 + k][r] + bhn4[k][r];
                float rg = fast_sigmoid(xr4[k][r] + ghr);
                float zg = fast_sigmoid(xz4[k][r] + ghz);
                float ng = fast_tanh(xn4[k][r] + rg * ghn);
                float hn = (1.f - zg) * ng + zg * h_old[k * 4 + r];
                h_old[k * 4 + r] = hn;
                hn4[k][r] = hn;
                if (layer == 2) {
                    mx[k * 4 + r] = fmaxf(mx[k * 4 + r], hn);
                    sm[k * 4 + r] += hn;
                }
            }
            union { f16x4 v; h2_t h[2]; } u;
            u.h[0] = pk(hn4[k][0], hn4[k][1]);
            u.h[1] = pk(hn4[k][2], hn4[k][3]);
            ph[k] = u.v;
        }
        if (m == 0) {
            _Float16* hnx = h16[(t & 1) ^ 1];
#pragma unroll
            for (int k = 0; k < 2; ++k) {
                const int jb = j0 + k * 16 + quad * 4;
                *(f16x4*)&hnx[jb] = ph[k];
                if (layer < 2) {
                    *(f16x4*)(yb16 + (size_t)t * DOUT + jb) = ph[k];
                    if (t == SEQT - 1)
                        *(float4*)&hT_all[layer * NB * 256 + b * 256 + jb]
                            = (float4){hn4[k][0], hn4[k][1], hn4[k][2], hn4[k][3]};
                }
            }
        }
        bar_lds();                               // publish h(t+1)
    }

    if (layer == 2) {
        // --- fused pooling + linear + softmax ---
        if (m == 0) {
#pragma unroll
            for (int k = 0; k < 2; ++k) {
                const int jb = j0 + k * 16 + quad * 4;
                *(f32x4*)&pool[512 + jb]  = (f32x4){h_old[k*4], h_old[k*4+1], h_old[k*4+2], h_old[k*4+3]};
                *(f32x4*)&pool[768 + jb]  = (f32x4){mx[k*4], mx[k*4+1], mx[k*4+2], mx[k*4+3]};
                *(f32x4*)&pool[1024 + jb] = (f32x4){sm[k*4] * (1.f/256.f), sm[k*4+1] * (1.f/256.f),
                                                    sm[k*4+2] * (1.f/256.f), sm[k*4+3] * (1.f/256.f)};
            }
        }
        if (tid < 256) {
            pool[tid]       = hT_all[b * 256 + tid];            // layer-0 hT
            pool[256 + tid] = hT_all[NB * 256 + b * 256 + tid]; // layer-1 hT
        }
        __syncthreads();
        if (tid < 256) {
            float p0 = 0.f, p1 = 0.f;
            for (int i = tid; i < 1280; i += 256) {
                float pv = pool[i];
                p0 = fmaf(lin_W[i], pv, p0);
                p1 = fmaf(lin_W[1280 + i], pv, p1);
            }
            red[tid] = p0; red[256 + tid] = p1;
        }
        __syncthreads();
        if (tid == 0) {
            float l0 = lin_b[0], l1 = lin_b[1];
            for (int i = 0; i < 256; ++i) { l0 += red[i]; l1 += red[256 + i]; }
            float m2 = fmaxf(l0, l1);
            float e0 = __expf(l0 - m2), e1 = __expf(l1 - m2);
            float s = e0 + e1;
            out[b * 2 + 0] = e0 / s;
            out[b * 2 + 1] = e1 / s;
        }
    }
}

// ---------------------------------------------------------------------------
extern "C" void kernel_launch(void* const* d_in, const int* in_sizes, int n_in,
                              void* d_out, int out_size, void* d_ws, size_t ws_size,
                              hipStream_t stream) {
    const float* x         = (const float*)d_in[0];
    const float* edge_attr = (const float*)d_in[1];
    const int*   ei        = (const int*)d_in[2];
    const float* WA        = (const float*)d_in[3];
    const float* WB        = (const float*)d_in[4];
    const float* gcn_bias  = (const float*)d_in[5];
    const float* w_ih[3] = {(const float*)d_in[6],  (const float*)d_in[10], (const float*)d_in[14]};
    const float* w_hh[3] = {(const float*)d_in[7],  (const float*)d_in[11], (const float*)d_in[15]};
    const float* b_ih[3] = {(const float*)d_in[8],  (const float*)d_in[12], (const float*)d_in[16]};
    const float* b_hh[3] = {(const float*)d_in[9],  (const float*)d_in[13], (const float*)d_in[17]};
    const float* lin_W = (const float*)d_in[18];
    const float* lin_b = (const float*)d_in[19];
    float* out = (float*)d_out;

    char* p = (char*)d_ws;
    auto alloc = [&](size_t bytes) {
        char* r = p;
        p += (bytes + 255) & ~(size_t)255;
        return r;
    };
    int*   deg    = (int*)alloc((size_t)NN * 4);   // ┐ contiguous: one memset
    int*   offs   = (int*)alloc((size_t)NN * 4);   // │
    int*   cursor = (int*)alloc((size_t)NN * 4);   // ┘
    float* dinv   = (float*)alloc((size_t)NN * 4);
    int*   eidx   = (int*)alloc((size_t)NE * 4);
    float* Bself  = (float*)alloc(256 * 4);
    float* hT     = (float*)alloc(2 * NB * 256 * 4);
    float* xp     = (float*)alloc((size_t)NN * G3 * 4);
    float* Ax     = xp;   // alias: Ax dead before xp is first written

    _Float16* node16 = (_Float16*)alloc((size_t)NN * DOUT * 2);
    _Float16* yA16   = (_Float16*)alloc((size_t)NN * DOUT * 2);
    _Float16* x16    = (_Float16*)alloc((size_t)NN * DOUT * 2);
    _Float16* yB16   = x16;  // alias: x16 dead after Ax GEMM, yB16 live later
    _Float16* WA16   = (_Float16*)alloc((size_t)256 * 256 * 2);
    _Float16* wih16[3];
    for (int l = 0; l < 3; ++l) wih16[l] = (_Float16*)alloc((size_t)G3 * 256 * 2);

    // --- CSR build + weight conversions ---
    hipMemsetAsync(deg, 0, (size_t)3 * NN * 4, stream);    // deg+offs+cursor
    k_count<<<NE / 256, 256, 0, stream>>>(ei, deg);
    k_scan_offs<<<1, 1024, 0, stream>>>(deg, offs, dinv);
    k_fill<<<NE / 256, 256, 0, stream>>>(ei, offs, cursor, eidx);
    k_bself<<<1, 256, 0, stream>>>(WB, Bself);
    k_cvt_all<<<4736, 256, 0, stream>>>(x, WA, w_ih[0], w_ih[1], w_ih[2],
                                        x16, WA16, wih16[0], wih16[1], wih16[2]);

    // --- GCN ---
    {
        dim3 g(NN / 128, 256 / 128);
        k_gemm16<<<g, 256, 0, stream>>>(x16, WA16, nullptr, Ax, NN, 256);
    }
    k_gcn<<<NN, 256, 0, stream>>>(Ax, WB, edge_attr, ei, eidx, offs, deg, dinv,
                                  Bself, gcn_bias, node16);

    // --- GRU x3 (layer 2 fuses pooling+linear+softmax) ---
    const _Float16* in16 = node16;
    _Float16* y16_outs[3] = {yA16, yB16, yA16};
    for (int l = 0; l < 3; ++l) {
        dim3 g(NN / 128, G3 / 128);
        k_gemm16<<<g, 256, 0, stream>>>(in16, wih16[l], b_ih[l], xp, NN, G3);
        k_gru_scan<<<NB, 512, 0, stream>>>(xp, w_hh[l], b_hh[l], y16_outs[l],
                                           hT, l, lin_W, lin_b, out);
        in16 = y16_outs[l];
    }
}

// Round 13
// 2146.584 us; speedup vs baseline: 1.7703x; 1.7703x over previous
//
#include <hip/hip_runtime.h>
#include <math.h>

#define NN   16384      // total nodes
#define NE   262144     // edges (no self loops)
#define NB   64         // graphs
#define SEQT 256        // nodes per graph (= seq len)
#define DEP  64
#define DOUT 256        // = HID
#define G3   768        // 3*HID
#define GK   256        // GEMM K (always 256 here)
#define ECAP 32         // GCN edges staged per chunk

typedef _Float16 h2_t   __attribute__((ext_vector_type(2)));
typedef _Float16 f16x4  __attribute__((ext_vector_type(4)));
typedef _Float16 f16x8  __attribute__((ext_vector_type(8)));
typedef float    f32x4  __attribute__((ext_vector_type(4)));

static __device__ __forceinline__ h2_t pk(float a, float b) {
    return (h2_t)__builtin_amdgcn_cvt_pkrtz(a, b);
}

static __device__ __forceinline__ float fast_sigmoid(float v) {
    return __builtin_amdgcn_rcpf(1.f + __expf(-v));
}
static __device__ __forceinline__ float fast_tanh(float v) {
    return 1.f - 2.f * __builtin_amdgcn_rcpf(1.f + __expf(2.f * v));
}

// barrier with LDS-only drain (no vmcnt: in-flight global loads/stores cross)
static __device__ __forceinline__ void bar_lds() {
    asm volatile("s_waitcnt lgkmcnt(0)\n\ts_barrier" ::: "memory");
}

// ---------------------------------------------------------------------------
// degree / CSR build (deg zero-initialized by memset; holds RAW in-degree)
// ---------------------------------------------------------------------------
__global__ void k_count(const int* __restrict__ ei, int* deg) {
    int e = blockIdx.x * 256 + threadIdx.x;
    if (e < NE) atomicAdd(&deg[ei[NE + e]], 1);   // col = dst
}

__global__ __launch_bounds__(1024) void k_scan_offs(const int* __restrict__ deg,
                                                    int* __restrict__ offs,
                                                    float* __restrict__ dinv) {
    __shared__ int lds[1024];
    const int tid = threadIdx.x;
    const int v0 = tid * 16;
    int loc[16];
    int s = 0;
#pragma unroll
    for (int i = 0; i < 16; ++i) {
        int d = deg[v0 + i];                      // raw in-edges
        loc[i] = s;
        s += d;
        dinv[v0 + i] = rsqrtf((float)(d + 1));    // +1 self loop
    }
    lds[tid] = s;
    __syncthreads();
    for (int off = 1; off < 1024; off <<= 1) {
        int x = (tid >= off) ? lds[tid - off] : 0;
        __syncthreads();
        lds[tid] += x;
        __syncthreads();
    }
    int base = lds[tid] - s;                      // exclusive prefix of this thread
#pragma unroll
    for (int i = 0; i < 16; ++i) offs[v0 + i] = base + loc[i];
}

__global__ void k_fill(const int* __restrict__ ei, const int* __restrict__ offs,
                       int* cursor, int* __restrict__ eidx) {
    int e = blockIdx.x * 256 + threadIdx.x;
    if (e < NE) {
        int c = ei[NE + e];
        int pos = offs[c] + atomicAdd(&cursor[c], 1);
        eidx[pos] = e;
    }
}

__global__ void k_bself(const float* __restrict__ WB, float* Bself) {
    int f = threadIdx.x;                          // 256 threads
    float s = 0.f;
#pragma unroll
    for (int d = 0; d < DEP; ++d) s += WB[f * DEP + d];
    Bself[f] = s;
}

// bias fold: bias768[l][j] = b_ih[j] + (j<512 ? b_hh[j] : 0)   (b_hn stays
// separate: the reference scales it by r before adding)
__global__ void k_bias_fold(const float* __restrict__ bi0, const float* __restrict__ bh0,
                            const float* __restrict__ bi1, const float* __restrict__ bh1,
                            const float* __restrict__ bi2, const float* __restrict__ bh2,
                            float* __restrict__ o) {
    int j = blockIdx.x * 256 + threadIdx.x;       // 9 blocks x 256 = 2304
    int l = j / G3, r = j % G3;
    const float* bi = (l == 0) ? bi0 : (l == 1) ? bi1 : bi2;
    const float* bh = (l == 0) ? bh0 : (l == 1) ? bh1 : bh2;
    o[j] = bi[r] + (r < 512 ? bh[r] : 0.f);
}

// ---------------------------------------------------------------------------
// one fused fp32->f16 conversion over all 5 regions
// ---------------------------------------------------------------------------
__global__ void k_cvt_all(const float* __restrict__ x,  const float* __restrict__ wa,
                          const float* __restrict__ w0, const float* __restrict__ w1,
                          const float* __restrict__ w2,
                          _Float16* __restrict__ xo,  _Float16* __restrict__ wao,
                          _Float16* __restrict__ w0o, _Float16* __restrict__ w1o,
                          _Float16* __restrict__ w2o) {
    size_t i = ((size_t)blockIdx.x * 256 + threadIdx.x) * 4;
    const size_t B0 = 4194304, B1 = B0 + 65536, B2 = B1 + 196608, B3 = B2 + 196608;
    const float* in; _Float16* out; size_t off;
    if      (i < B0) { in = x;  out = xo;  off = i; }
    else if (i < B1) { in = wa; out = wao; off = i - B0; }
    else if (i < B2) { in = w0; out = w0o; off = i - B1; }
    else if (i < B3) { in = w1; out = w1o; off = i - B2; }
    else             { in = w2; out = w2o; off = i - B3; }
    float4 v = *(const float4*)(in + off);
    *(h2_t*)(out + off)     = pk(v.x, v.y);
    *(h2_t*)(out + off + 2) = pk(v.z, v.w);
}

// ---------------------------------------------------------------------------
// MFMA f16 GEMM: C[M,N] = A16[M,256] @ B16[N,256]^T (+ bias).
// F16OUT: store f16 (used for xp); else fp32 (used for Ax).
// ---------------------------------------------------------------------------
template <bool F16OUT>
__global__ __launch_bounds__(256) void k_gemm16(const _Float16* __restrict__ A16,
                                                const _Float16* __restrict__ B16,
                                                const float* __restrict__ bias,
                                                void* __restrict__ Cout,
                                                int M, int N) {
    const int tid  = threadIdx.x;
    const int lane = tid & 63;
    const int wv   = tid >> 6;
    const int m0   = blockIdx.x * 128 + wv * 32;
    const int n0   = blockIdx.y * 128;
    const int ml   = lane & 15;
    const int quad = lane >> 4;

    const _Float16* ap0 = A16 + (size_t)(m0 + ml) * GK + quad * 8;
    const _Float16* ap1 = ap0 + (size_t)16 * GK;
    const _Float16* bp0 = B16 + (size_t)(n0 + ml) * GK + quad * 8;

    f32x4 acc[2][8];
#pragma unroll
    for (int i = 0; i < 2; ++i)
#pragma unroll
        for (int j = 0; j < 8; ++j) acc[i][j] = (f32x4){0.f, 0.f, 0.f, 0.f};

#pragma unroll 2
    for (int k0 = 0; k0 < GK; k0 += 32) {
        f16x8 a0 = *(const f16x8*)(ap0 + k0);
        f16x8 a1 = *(const f16x8*)(ap1 + k0);
#pragma unroll
        for (int nf = 0; nf < 8; ++nf) {
            f16x8 bf = *(const f16x8*)(bp0 + (size_t)nf * 16 * GK + k0);
            acc[0][nf] = __builtin_amdgcn_mfma_f32_16x16x32_f16(a0, bf, acc[0][nf], 0, 0, 0);
            acc[1][nf] = __builtin_amdgcn_mfma_f32_16x16x32_f16(a1, bf, acc[1][nf], 0, 0, 0);
        }
    }

#pragma unroll
    for (int mf = 0; mf < 2; ++mf)
#pragma unroll
        for (int nf = 0; nf < 8; ++nf) {
            const int col = n0 + nf * 16 + ml;
            const float bv = bias ? bias[col] : 0.f;
#pragma unroll
            for (int r = 0; r < 4; ++r) {
                const int row = m0 + mf * 16 + quad * 4 + r;
                float v = acc[mf][nf][r] + bv;
                if (F16OUT)
                    ((_Float16*)Cout)[(size_t)row * N + col] = (_Float16)v;
                else
                    ((float*)Cout)[(size_t)row * N + col] = v;
            }
        }
}

// ---------------------------------------------------------------------------
// GCN gather v2: chunked LDS staging, fast_tanh.
// ---------------------------------------------------------------------------
__global__ __launch_bounds__(256) void k_gcn(const float* __restrict__ Ax,
                                             const float* __restrict__ WB,
                                             const float* __restrict__ edge_attr,
                                             const int* __restrict__ ei,
                                             const int* __restrict__ eidx,
                                             const int* __restrict__ offs,
                                             const int* __restrict__ deg,
                                             const float* __restrict__ dinv,
                                             const float* __restrict__ Bself,
                                             const float* __restrict__ gcn_bias,
                                             _Float16* __restrict__ node16) {
    const int v = blockIdx.x;
    const int f = threadIdx.x;

    float wb[64];
#pragma unroll
    for (int d4 = 0; d4 < 16; ++d4) {
        float4 t = *(const float4*)&WB[f * DEP + d4 * 4];
        wb[d4 * 4 + 0] = t.x; wb[d4 * 4 + 1] = t.y;
        wb[d4 * 4 + 2] = t.z; wb[d4 * 4 + 3] = t.w;
    }

    __shared__ float ea_s[ECAP * 64];
    __shared__ int   es_s[ECAP];
    __shared__ int   src_s[ECAP];
    __shared__ float nrm_s[ECAP];

    const int   base = offs[v];
    const int   cnt  = deg[v];                   // raw in-edges
    const float dv   = dinv[v];
    float acc = 0.f;

    for (int c0 = 0; c0 < cnt; c0 += ECAP) {
        const int n = min(ECAP, cnt - c0);
        if (f < n) {
            int e = eidx[base + c0 + f];
            es_s[f] = e;
            int s = ei[e];
            src_s[f] = s;
            nrm_s[f] = dinv[s] * dv;
        }
        __syncthreads();
        for (int idx = f; idx < n * 64; idx += 256) {
            int el = idx >> 6, d = idx & 63;
            ea_s[idx] = edge_attr[(size_t)es_s[el] * DEP + d];
        }
        __syncthreads();
        for (int i = 0; i < n; ++i) {
            float ax = Ax[(size_t)src_s[i] * DOUT + f];   // issued early
            float be = 0.f;
#pragma unroll
            for (int d = 0; d < 64; ++d) be = fmaf(wb[d], ea_s[i * 64 + d], be);
            acc = fmaf(nrm_s[i], fast_tanh(ax * be), acc);
        }
        __syncthreads();                          // before chunk overwrite
    }
    // self loop: norm = dinv^2, Be = rowsum(WB)
    acc += dv * dv * fast_tanh(Ax[(size_t)v * DOUT + f] * Bself[f]);
    float nv = fast_tanh(acc / (float)(cnt + 1) + gcn_bias[f]);
    node16[(size_t)v * DOUT + f] = (_Float16)nv;
}

// ---------------------------------------------------------------------------
// GRU scan v10 (register-shaved in-register gate): 512-thr WG, 2 waves/SIMD.
// v9 (R12) spilled (~300 regs > 256 budget).  Shaved: b_hr/b_hz folded into
// the xp GEMM bias (-16), xp f16 (-12), b_hn via LDS (-8), mx/sm removed
// from loop (-16; LAST does pooling epilogue re-reading own y16).
// Loop-live ~ 192(A)+24(C)+8(B)+12(xp)+8(h_old)+4(ph)+misc ~ 256 budget.
// ---------------------------------------------------------------------------
template <bool LAST>
__global__ __launch_bounds__(512, 2) void k_gru_scan_t(
        const _Float16* __restrict__ xp16,
        const float* __restrict__ w_hh,
        const float* __restrict__ b_hh,
        _Float16* __restrict__ y16,
        float* __restrict__ hT_all,
        int layer,
        const float* __restrict__ lin_W,
        const float* __restrict__ lin_b,
        float* __restrict__ out) {
    const int tid  = threadIdx.x;
    const int b    = blockIdx.x;                 // graph
    const int lane = tid & 63;
    const int wv   = tid >> 6;                   // wave 0..7
    const int m    = lane & 15;                  // A-frag row within 16
    const int quad = lane >> 4;                  // 0..3 (k-subgroup)
    const int j0   = wv * 32;                    // this wave's gate rows

    // row-block map: rb 0,1 -> r-gate; 2,3 -> z-gate; 4,5 -> n-gate
    int rbmap[6];
#pragma unroll
    for (int g = 0; g < 3; ++g) {
        rbmap[2 * g]     = g * 16 + 2 * wv;
        rbmap[2 * g + 1] = g * 16 + 2 * wv + 1;
    }

    // --- weights -> A-fragments (one-time global read, fp32 -> f16) ---
    f16x8 A[6][8];
#pragma unroll
    for (int rb = 0; rb < 6; ++rb) {
        const int row = rbmap[rb] * 16 + m;
#pragma unroll
        for (int kt = 0; kt < 8; ++kt) {
            const float* wp = w_hh + (size_t)row * 256 + kt * 32 + quad * 8;
            float4 a0 = *(const float4*)wp;
            float4 a1 = *(const float4*)(wp + 4);
            union { f16x8 v; h2_t h[4]; } u;
            u.h[0] = pk(a0.x, a0.y); u.h[1] = pk(a0.z, a0.w);
            u.h[2] = pk(a1.x, a1.y); u.h[3] = pk(a1.z, a1.w);
            A[rb][kt] = u.v;
        }
    }

    __shared__ _Float16 h16[2][256];             // h(t) f16, double-buffered
    __shared__ float    bhnL[256];               // b_hn (LDS, saves 8 regs)
    __shared__ float    pool[1280];              // LAST epilogue only
    __shared__ float    red[512];
    float h_old[8];
#pragma unroll
    for (int i = 0; i < 8; ++i) h_old[i] = 0.f;
    if (tid < 256) {
        h16[0][tid] = (_Float16)0.f;
        bhnL[tid]   = b_hh[512 + tid];
    }
    __syncthreads();

    const _Float16* xpb  = xp16 + (size_t)b * SEQT * G3;
    _Float16*       yb16 = y16  + (size_t)b * SEQT * DOUT;

    for (int t = 0; t < SEQT; ++t) {
        // prefetch this step's xp (f16, biases pre-folded for r/z gates)
        const _Float16* xpt = xpb + (size_t)t * G3;
        f16x4 xr4[2], xz4[2], xn4[2];
#pragma unroll
        for (int k = 0; k < 2; ++k) {
            const int jb = j0 + k * 16 + quad * 4;
            xr4[k] = *(const f16x4*)(xpt + jb);
            xz4[k] = *(const f16x4*)(xpt + 256 + jb);
            xn4[k] = *(const f16x4*)(xpt + 512 + jb);
        }
        // b_hn for this lane's js (LDS)
        float4 bhn4[2];
#pragma unroll
        for (int k = 0; k < 2; ++k)
            bhn4[k] = *(const float4*)&bhnL[j0 + k * 16 + quad * 4];

        // k-outer MFMA: one B-frag per kt feeds 6 independent chains
        const _Float16* hcur = h16[t & 1];
        f32x4 C[6];
#pragma unroll
        for (int rb = 0; rb < 6; ++rb) C[rb] = (f32x4){0.f, 0.f, 0.f, 0.f};

        union { f16x8 v; float4 f; } Bk, Bn;
        Bk.f = *(const float4*)&hcur[quad * 8];
#pragma unroll
        for (int kt = 0; kt < 8; ++kt) {
            if (kt < 7) Bn.f = *(const float4*)&hcur[(kt + 1) * 32 + quad * 8];
#pragma unroll
            for (int rb = 0; rb < 6; ++rb)
                C[rb] = __builtin_amdgcn_mfma_f32_16x16x32_f16(A[rb][kt], Bk.v, C[rb], 0, 0, 0);
            Bk.v = Bn.v;
        }

        // in-register gate for the lane's 8 js (identical across m lanes)
        f16x4 ph[2];
        float hn4[2][4];
#pragma unroll
        for (int k = 0; k < 2; ++k) {
#pragma unroll
            for (int r = 0; r < 4; ++r) {
                float ghn = C[4 + k][r] + bhn4[k][r];
                float rg = fast_sigmoid((float)xr4[k][r] + C[k][r]);
                float zg = fast_sigmoid((float)xz4[k][r] + C[2 + k][r]);
                float ng = fast_tanh((float)xn4[k][r] + rg * ghn);
                float hn = (1.f - zg) * ng + zg * h_old[k * 4 + r];
                h_old[k * 4 + r] = hn;
                hn4[k][r] = hn;
            }
            union { f16x4 v; h2_t h[2]; } u;
            u.h[0] = pk(hn4[k][0], hn4[k][1]);
            u.h[1] = pk(hn4[k][2], hn4[k][3]);
            ph[k] = u.v;
        }
        if (m == 0) {
            _Float16* hnx = h16[(t & 1) ^ 1];
#pragma unroll
            for (int k = 0; k < 2; ++k) {
                const int jb = j0 + k * 16 + quad * 4;
                *(f16x4*)&hnx[jb] = ph[k];
                *(f16x4*)(yb16 + (size_t)t * DOUT + jb) = ph[k];
                if (!LAST && t == SEQT - 1)
                    *(float4*)&hT_all[layer * NB * 256 + b * 256 + jb]
                        = (float4){hn4[k][0], hn4[k][1], hn4[k][2], hn4[k][3]};
            }
        }
        bar_lds();                               // publish h(t+1)
    }

    if (LAST) {
        // --- fused pooling + linear + softmax ---
        if (m == 0) {
#pragma unroll
            for (int k = 0; k < 2; ++k) {
                const int jb = j0 + k * 16 + quad * 4;
                *(f32x4*)&pool[512 + jb] = (f32x4){h_old[k*4], h_old[k*4+1],
                                                   h_old[k*4+2], h_old[k*4+3]};
            }
        }
        __syncthreads();                         // drains vmcnt: y16 stores done
        if (tid < 256) {
            float mx = -1e30f, sm = 0.f;
            for (int t = 0; t < SEQT; ++t) {
                float v = (float)yb16[(size_t)t * DOUT + tid];  // own writes
                mx = fmaxf(mx, v);
                sm += v;
            }
            pool[768 + tid]  = mx;
            pool[1024 + tid] = sm * (1.f / 256.f);
            pool[tid]        = hT_all[b * 256 + tid];            // layer-0 hT
            pool[256 + tid]  = hT_all[NB * 256 + b * 256 + tid]; // layer-1 hT
        }
        __syncthreads();
        if (tid < 256) {
            float p0 = 0.f, p1 = 0.f;
            for (int i = tid; i < 1280; i += 256) {
                float pv = pool[i];
                p0 = fmaf(lin_W[i], pv, p0);
                p1 = fmaf(lin_W[1280 + i], pv, p1);
            }
            red[tid] = p0; red[256 + tid] = p1;
        }
        __syncthreads();
        if (tid == 0) {
            float l0 = lin_b[0], l1 = lin_b[1];
            for (int i = 0; i < 256; ++i) { l0 += red[i]; l1 += red[256 + i]; }
            float m2 = fmaxf(l0, l1);
            float e0 = __expf(l0 - m2), e1 = __expf(l1 - m2);
            float s = e0 + e1;
            out[b * 2 + 0] = e0 / s;
            out[b * 2 + 1] = e1 / s;
        }
    }
}

// ---------------------------------------------------------------------------
extern "C" void kernel_launch(void* const* d_in, const int* in_sizes, int n_in,
                              void* d_out, int out_size, void* d_ws, size_t ws_size,
                              hipStream_t stream) {
    const float* x         = (const float*)d_in[0];
    const float* edge_attr = (const float*)d_in[1];
    const int*   ei        = (const int*)d_in[2];
    const float* WA        = (const float*)d_in[3];
    const float* WB        = (const float*)d_in[4];
    const float* gcn_bias  = (const float*)d_in[5];
    const float* w_ih[3] = {(const float*)d_in[6],  (const float*)d_in[10], (const float*)d_in[14]};
    const float* w_hh[3] = {(const float*)d_in[7],  (const float*)d_in[11], (const float*)d_in[15]};
    const float* b_ih[3] = {(const float*)d_in[8],  (const float*)d_in[12], (const float*)d_in[16]};
    const float* b_hh[3] = {(const float*)d_in[9],  (const float*)d_in[13], (const float*)d_in[17]};
    const float* lin_W = (const float*)d_in[18];
    const float* lin_b = (const float*)d_in[19];
    float* out = (float*)d_out;

    char* p = (char*)d_ws;
    auto alloc = [&](size_t bytes) {
        char* r = p;
        p += (bytes + 255) & ~(size_t)255;
        return r;
    };
    int*   deg    = (int*)alloc((size_t)NN * 4);   // ┐ contiguous: one memset
    int*   offs   = (int*)alloc((size_t)NN * 4);   // │
    int*   cursor = (int*)alloc((size_t)NN * 4);   // ┘
    float* dinv   = (float*)alloc((size_t)NN * 4);
    int*   eidx   = (int*)alloc((size_t)NE * 4);
    float* Bself  = (float*)alloc(256 * 4);
    float* hT     = (float*)alloc(2 * NB * 256 * 4);
    float* bias768 = (float*)alloc(3 * G3 * 4);
    float* Ax     = (float*)alloc((size_t)NN * DOUT * 4);
    _Float16* xp16 = (_Float16*)alloc((size_t)NN * G3 * 2);

    _Float16* node16 = (_Float16*)alloc((size_t)NN * DOUT * 2);
    _Float16* yA16   = (_Float16*)alloc((size_t)NN * DOUT * 2);
    _Float16* x16    = (_Float16*)alloc((size_t)NN * DOUT * 2);
    _Float16* yB16   = x16;  // alias: x16 dead after Ax GEMM, yB16 live later
    _Float16* WA16   = (_Float16*)alloc((size_t)256 * 256 * 2);
    _Float16* wih16[3];
    for (int l = 0; l < 3; ++l) wih16[l] = (_Float16*)alloc((size_t)G3 * 256 * 2);

    // --- CSR build + weight conversions + bias fold ---
    hipMemsetAsync(deg, 0, (size_t)3 * NN * 4, stream);    // deg+offs+cursor
    k_count<<<NE / 256, 256, 0, stream>>>(ei, deg);
    k_scan_offs<<<1, 1024, 0, stream>>>(deg, offs, dinv);
    k_fill<<<NE / 256, 256, 0, stream>>>(ei, offs, cursor, eidx);
    k_bself<<<1, 256, 0, stream>>>(WB, Bself);
    k_bias_fold<<<9, 256, 0, stream>>>(b_ih[0], b_hh[0], b_ih[1], b_hh[1],
                                       b_ih[2], b_hh[2], bias768);
    k_cvt_all<<<4736, 256, 0, stream>>>(x, WA, w_ih[0], w_ih[1], w_ih[2],
                                        x16, WA16, wih16[0], wih16[1], wih16[2]);

    // --- GCN ---
    {
        dim3 g(NN / 128, 256 / 128);
        k_gemm16<false><<<g, 256, 0, stream>>>(x16, WA16, nullptr, Ax, NN, 256);
    }
    k_gcn<<<NN, 256, 0, stream>>>(Ax, WB, edge_attr, ei, eidx, offs, deg, dinv,
                                  Bself, gcn_bias, node16);

    // --- GRU x3 (layer 2 fuses pooling+linear+softmax) ---
    const _Float16* in16 = node16;
    _Float16* y16_outs[3] = {yA16, yB16, yA16};
    for (int l = 0; l < 3; ++l) {
        dim3 g(NN / 128, G3 / 128);
        k_gemm16<true><<<g, 256, 0, stream>>>(in16, wih16[l], bias768 + l * G3,
                                              xp16, NN, G3);
        if (l < 2)
            k_gru_scan_t<false><<<NB, 512, 0, stream>>>(xp16, w_hh[l], b_hh[l],
                                                        y16_outs[l], hT, l,
                                                        lin_W, lin_b, out);
        else
            k_gru_scan_t<true><<<NB, 512, 0, stream>>>(xp16, w_hh[l], b_hh[l],
                                                       y16_outs[l], hT, l,
                                                       lin_W, lin_b, out);
        in16 = y16_outs[l];
    }
}

// Round 14
// 1666.507 us; speedup vs baseline: 2.2803x; 1.2881x over previous
//
#include <hip/hip_runtime.h>
#include <math.h>

#define NN   16384      // total nodes
#define NE   262144     // edges (no self loops)
#define NB   64         // graphs
#define SEQT 256        // nodes per graph (= seq len)
#define DEP  64
#define DOUT 256        // = HID
#define G3   768        // 3*HID
#define GK   256        // GEMM K (always 256 here)
#define ECAP 32         // GCN edges staged per chunk

typedef _Float16 h2_t   __attribute__((ext_vector_type(2)));
typedef _Float16 f16x4  __attribute__((ext_vector_type(4)));
typedef _Float16 f16x8  __attribute__((ext_vector_type(8)));
typedef float    f32x4  __attribute__((ext_vector_type(4)));

static __device__ __forceinline__ h2_t pk(float a, float b) {
    return (h2_t)__builtin_amdgcn_cvt_pkrtz(a, b);
}

static __device__ __forceinline__ float fast_sigmoid(float v) {
    return __builtin_amdgcn_rcpf(1.f + __expf(-v));
}
static __device__ __forceinline__ float fast_tanh(float v) {
    return 1.f - 2.f * __builtin_amdgcn_rcpf(1.f + __expf(2.f * v));
}

// barrier with LDS-only drain (no vmcnt: in-flight global loads/stores cross)
static __device__ __forceinline__ void bar_lds() {
    asm volatile("s_waitcnt lgkmcnt(0)\n\ts_barrier" ::: "memory");
}

// ---------------------------------------------------------------------------
// degree / CSR build (deg zero-initialized by memset; holds RAW in-degree)
// ---------------------------------------------------------------------------
__global__ void k_count(const int* __restrict__ ei, int* deg) {
    int e = blockIdx.x * 256 + threadIdx.x;
    if (e < NE) atomicAdd(&deg[ei[NE + e]], 1);   // col = dst
}

__global__ __launch_bounds__(1024) void k_scan_offs(const int* __restrict__ deg,
                                                    int* __restrict__ offs,
                                                    float* __restrict__ dinv) {
    __shared__ int lds[1024];
    const int tid = threadIdx.x;
    const int v0 = tid * 16;
    int loc[16];
    int s = 0;
#pragma unroll
    for (int i = 0; i < 16; ++i) {
        int d = deg[v0 + i];                      // raw in-edges
        loc[i] = s;
        s += d;
        dinv[v0 + i] = rsqrtf((float)(d + 1));    // +1 self loop
    }
    lds[tid] = s;
    __syncthreads();
    for (int off = 1; off < 1024; off <<= 1) {
        int x = (tid >= off) ? lds[tid - off] : 0;
        __syncthreads();
        lds[tid] += x;
        __syncthreads();
    }
    int base = lds[tid] - s;                      // exclusive prefix of this thread
#pragma unroll
    for (int i = 0; i < 16; ++i) offs[v0 + i] = base + loc[i];
}

__global__ void k_fill(const int* __restrict__ ei, const int* __restrict__ offs,
                       int* cursor, int* __restrict__ eidx) {
    int e = blockIdx.x * 256 + threadIdx.x;
    if (e < NE) {
        int c = ei[NE + e];
        int pos = offs[c] + atomicAdd(&cursor[c], 1);
        eidx[pos] = e;
    }
}

__global__ void k_bself(const float* __restrict__ WB, float* Bself) {
    int f = threadIdx.x;                          // 256 threads
    float s = 0.f;
#pragma unroll
    for (int d = 0; d < DEP; ++d) s += WB[f * DEP + d];
    Bself[f] = s;
}

// bias fold: bias768[l][j] = b_ih[j] + (j<512 ? b_hh[j] : 0)   (b_hn stays
// separate: the reference scales it by r before adding)
__global__ void k_bias_fold(const float* __restrict__ bi0, const float* __restrict__ bh0,
                            const float* __restrict__ bi1, const float* __restrict__ bh1,
                            const float* __restrict__ bi2, const float* __restrict__ bh2,
                            float* __restrict__ o) {
    int j = blockIdx.x * 256 + threadIdx.x;       // 9 blocks x 256 = 2304
    int l = j / G3, r = j % G3;
    const float* bi = (l == 0) ? bi0 : (l == 1) ? bi1 : bi2;
    const float* bh = (l == 0) ? bh0 : (l == 1) ? bh1 : bh2;
    o[j] = bi[r] + (r < 512 ? bh[r] : 0.f);
}

// ---------------------------------------------------------------------------
// one fused fp32->f16 conversion over all 5 regions
// ---------------------------------------------------------------------------
__global__ void k_cvt_all(const float* __restrict__ x,  const float* __restrict__ wa,
                          const float* __restrict__ w0, const float* __restrict__ w1,
                          const float* __restrict__ w2,
                          _Float16* __restrict__ xo,  _Float16* __restrict__ wao,
                          _Float16* __restrict__ w0o, _Float16* __restrict__ w1o,
                          _Float16* __restrict__ w2o) {
    size_t i = ((size_t)blockIdx.x * 256 + threadIdx.x) * 4;
    const size_t B0 = 4194304, B1 = B0 + 65536, B2 = B1 + 196608, B3 = B2 + 196608;
    const float* in; _Float16* out; size_t off;
    if      (i < B0) { in = x;  out = xo;  off = i; }
    else if (i < B1) { in = wa; out = wao; off = i - B0; }
    else if (i < B2) { in = w0; out = w0o; off = i - B1; }
    else if (i < B3) { in = w1; out = w1o; off = i - B2; }
    else             { in = w2; out = w2o; off = i - B3; }
    float4 v = *(const float4*)(in + off);
    *(h2_t*)(out + off)     = pk(v.x, v.y);
    *(h2_t*)(out + off + 2) = pk(v.z, v.w);
}

// ---------------------------------------------------------------------------
// MFMA f16 GEMM: C[M,N] = A16[M,256] @ B16[N,256]^T (+ bias).
// F16OUT: store f16 (used for xp); else fp32 (used for Ax).
// ---------------------------------------------------------------------------
template <bool F16OUT>
__global__ __launch_bounds__(256) void k_gemm16(const _Float16* __restrict__ A16,
                                                const _Float16* __restrict__ B16,
                                                const float* __restrict__ bias,
                                                void* __restrict__ Cout,
                                                int M, int N) {
    const int tid  = threadIdx.x;
    const int lane = tid & 63;
    const int wv   = tid >> 6;
    const int m0   = blockIdx.x * 128 + wv * 32;
    const int n0   = blockIdx.y * 128;
    const int ml   = lane & 15;
    const int quad = lane >> 4;

    const _Float16* ap0 = A16 + (size_t)(m0 + ml) * GK + quad * 8;
    const _Float16* ap1 = ap0 + (size_t)16 * GK;
    const _Float16* bp0 = B16 + (size_t)(n0 + ml) * GK + quad * 8;

    f32x4 acc[2][8];
#pragma unroll
    for (int i = 0; i < 2; ++i)
#pragma unroll
        for (int j = 0; j < 8; ++j) acc[i][j] = (f32x4){0.f, 0.f, 0.f, 0.f};

#pragma unroll 2
    for (int k0 = 0; k0 < GK; k0 += 32) {
        f16x8 a0 = *(const f16x8*)(ap0 + k0);
        f16x8 a1 = *(const f16x8*)(ap1 + k0);
#pragma unroll
        for (int nf = 0; nf < 8; ++nf) {
            f16x8 bf = *(const f16x8*)(bp0 + (size_t)nf * 16 * GK + k0);
            acc[0][nf] = __builtin_amdgcn_mfma_f32_16x16x32_f16(a0, bf, acc[0][nf], 0, 0, 0);
            acc[1][nf] = __builtin_amdgcn_mfma_f32_16x16x32_f16(a1, bf, acc[1][nf], 0, 0, 0);
        }
    }

#pragma unroll
    for (int mf = 0; mf < 2; ++mf)
#pragma unroll
        for (int nf = 0; nf < 8; ++nf) {
            const int col = n0 + nf * 16 + ml;
            const float bv = bias ? bias[col] : 0.f;
#pragma unroll
            for (int r = 0; r < 4; ++r) {
                const int row = m0 + mf * 16 + quad * 4 + r;
                float v = acc[mf][nf][r] + bv;
                if (F16OUT)
                    ((_Float16*)Cout)[(size_t)row * N + col] = (_Float16)v;
                else
                    ((float*)Cout)[(size_t)row * N + col] = v;
            }
        }
}

// ---------------------------------------------------------------------------
// GCN gather v2: chunked LDS staging, fast_tanh.
// ---------------------------------------------------------------------------
__global__ __launch_bounds__(256) void k_gcn(const float* __restrict__ Ax,
                                             const float* __restrict__ WB,
                                             const float* __restrict__ edge_attr,
                                             const int* __restrict__ ei,
                                             const int* __restrict__ eidx,
                                             const int* __restrict__ offs,
                                             const int* __restrict__ deg,
                                             const float* __restrict__ dinv,
                                             const float* __restrict__ Bself,
                                             const float* __restrict__ gcn_bias,
                                             _Float16* __restrict__ node16) {
    const int v = blockIdx.x;
    const int f = threadIdx.x;

    float wb[64];
#pragma unroll
    for (int d4 = 0; d4 < 16; ++d4) {
        float4 t = *(const float4*)&WB[f * DEP + d4 * 4];
        wb[d4 * 4 + 0] = t.x; wb[d4 * 4 + 1] = t.y;
        wb[d4 * 4 + 2] = t.z; wb[d4 * 4 + 3] = t.w;
    }

    __shared__ float ea_s[ECAP * 64];
    __shared__ int   es_s[ECAP];
    __shared__ int   src_s[ECAP];
    __shared__ float nrm_s[ECAP];

    const int   base = offs[v];
    const int   cnt  = deg[v];                   // raw in-edges
    const float dv   = dinv[v];
    float acc = 0.f;

    for (int c0 = 0; c0 < cnt; c0 += ECAP) {
        const int n = min(ECAP, cnt - c0);
        if (f < n) {
            int e = eidx[base + c0 + f];
            es_s[f] = e;
            int s = ei[e];
            src_s[f] = s;
            nrm_s[f] = dinv[s] * dv;
        }
        __syncthreads();
        for (int idx = f; idx < n * 64; idx += 256) {
            int el = idx >> 6, d = idx & 63;
            ea_s[idx] = edge_attr[(size_t)es_s[el] * DEP + d];
        }
        __syncthreads();
        for (int i = 0; i < n; ++i) {
            float ax = Ax[(size_t)src_s[i] * DOUT + f];   // issued early
            float be = 0.f;
#pragma unroll
            for (int d = 0; d < 64; ++d) be = fmaf(wb[d], ea_s[i * 64 + d], be);
            acc = fmaf(nrm_s[i], fast_tanh(ax * be), acc);
        }
        __syncthreads();                          // before chunk overwrite
    }
    // self loop: norm = dinv^2, Be = rowsum(WB)
    acc += dv * dv * fast_tanh(Ax[(size_t)v * DOUT + f] * Bself[f]);
    float nv = fast_tanh(acc / (float)(cnt + 1) + gcn_bias[f]);
    node16[(size_t)v * DOUT + f] = (_Float16)nv;
}

// ---------------------------------------------------------------------------
// GRU scan (v8 core — proven 378 µs in R9/R11): 512-thr WG (8 waves =
// 2/SIMD) per graph; w_hh A-frags 48/wave = 192 regs (AGPR half of unified
// file, MFMA-native); k-outer MFMA, 6 indep chains; gh via LDS + 2 barriers.
// R12/R13's in-register gate abandoned: 192(A)+24(C)+~50(gate) > 256 budget
// -> scratch spill (2x-3x regression, twice).
// Kept from R13: xp is f16 (b_ih + b_hh[r,z] pre-folded by the GEMM bias);
// layer==2 fuses pooling+linear+softmax and skips the y16 store.
// ---------------------------------------------------------------------------
__global__ __launch_bounds__(512, 2) void k_gru_scan(const _Float16* __restrict__ xp16,
                                                     const float* __restrict__ w_hh,
                                                     const float* __restrict__ b_hh,
                                                     _Float16* __restrict__ y16,
                                                     float* __restrict__ hT_all,
                                                     int layer,
                                                     const float* __restrict__ lin_W,
                                                     const float* __restrict__ lin_b,
                                                     float* __restrict__ out) {
    const int tid  = threadIdx.x;
    const int b    = blockIdx.x;                 // graph
    const int lane = tid & 63;
    const int wv   = tid >> 6;                   // wave 0..7
    const int m    = lane & 15;                  // A-frag row within 16
    const int quad = lane >> 4;                  // 0..3 (k-subgroup)
    const bool gate = tid < 256;

    // --- weights -> A-fragments (one-time global read, fp32 -> f16) ---
    f16x8 A[6][8];
#pragma unroll
    for (int rb = 0; rb < 6; ++rb) {
        const int row = wv * 96 + rb * 16 + m;
#pragma unroll
        for (int kt = 0; kt < 8; ++kt) {
            const float* wp = w_hh + (size_t)row * 256 + kt * 32 + quad * 8;
            float4 a0 = *(const float4*)wp;
            float4 a1 = *(const float4*)(wp + 4);
            union { f16x8 v; h2_t h[4]; } u;
            u.h[0] = pk(a0.x, a0.y); u.h[1] = pk(a0.z, a0.w);
            u.h[2] = pk(a1.x, a1.y); u.h[3] = pk(a1.z, a1.w);
            A[rb][kt] = u.v;
        }
    }

    float bhn = 0.f;                             // only the n-gate hidden bias
    if (gate) bhn = b_hh[512 + tid];             // (r/z biases folded into xp)

    __shared__ _Float16 h16[2][256];             // h(t) f16, double-buffered
    __shared__ float    ghL[768];                // w_hh @ h
    __shared__ float    pool[1280];              // layer-2 epilogue only
    __shared__ float    red[512];
    float h_old = 0.f;                           // thread tid<256 owns h[tid]
    if (gate) h16[0][tid] = (_Float16)0.f;
    __syncthreads();

    const _Float16* xpb  = xp16 + (size_t)b * SEQT * G3;
    _Float16*       yb16 = y16  + (size_t)b * SEQT * DOUT;

    float mx = -1e30f, sm = 0.f;                 // layer-2 pooling accum

    for (int t = 0; t < SEQT; ++t) {
        // prefetch this step's xp (f16; waited at gate use, overlaps MFMA)
        float xr = 0.f, xz = 0.f, xn = 0.f;
        if (gate) {
            const _Float16* xpt = xpb + (size_t)t * G3 + tid;
            xr = (float)xpt[0]; xz = (float)xpt[256]; xn = (float)xpt[512];
        }

        // k-outer MFMA: one B-frag per kt feeds 6 independent chains
        const _Float16* hcur = h16[t & 1];
        f32x4 C[6];
#pragma unroll
        for (int rb = 0; rb < 6; ++rb) C[rb] = (f32x4){0.f, 0.f, 0.f, 0.f};

        union { f16x8 v; float4 f; } Bk, Bn;
        Bk.f = *(const float4*)&hcur[quad * 8];
#pragma unroll
        for (int kt = 0; kt < 8; ++kt) {
            if (kt < 7) Bn.f = *(const float4*)&hcur[(kt + 1) * 32 + quad * 8];
#pragma unroll
            for (int rb = 0; rb < 6; ++rb)
                C[rb] = __builtin_amdgcn_mfma_f32_16x16x32_f16(A[rb][kt], Bk.v, C[rb], 0, 0, 0);
            Bk.v = Bn.v;
        }
        if (m == 0) {                            // col-0 lanes hold the matvec
#pragma unroll
            for (int rb = 0; rb < 6; ++rb)
                *(f32x4*)&ghL[wv * 96 + rb * 16 + quad * 4] = C[rb];
        }
        bar_lds();                               // gh visible to gate waves

        if (gate) {
            const int j = tid;
            float r = fast_sigmoid(xr + ghL[j]);         // biases pre-folded
            float z = fast_sigmoid(xz + ghL[256 + j]);
            float n = fast_tanh(xn + r * (ghL[512 + j] + bhn));
            float hn = (1.f - z) * n + z * h_old;
            h_old = hn;
            h16[(t & 1) ^ 1][j] = (_Float16)hn;  // next step's buffer
            if (layer < 2) {
                yb16[(size_t)t * DOUT + j] = (_Float16)hn;
                if (t == SEQT - 1) hT_all[layer * NB * 256 + b * 256 + j] = hn;
            } else {
                mx = fmaxf(mx, hn);
                sm += hn;
            }
        }
        bar_lds();                               // publish h(t+1)
    }

    if (layer == 2) {
        // --- fused pooling + linear + softmax ---
        if (gate) {
            const int j = tid;
            pool[j]        = hT_all[b * 256 + j];               // layer-0 hT
            pool[256 + j]  = hT_all[NB * 256 + b * 256 + j];    // layer-1 hT
            pool[512 + j]  = h_old;                             // layer-2 hT
            pool[768 + j]  = mx;
            pool[1024 + j] = sm * (1.f / 256.f);
        }
        __syncthreads();
        if (gate) {
            float p0 = 0.f, p1 = 0.f;
            for (int i = tid; i < 1280; i += 256) {
                float pv = pool[i];
                p0 = fmaf(lin_W[i], pv, p0);
                p1 = fmaf(lin_W[1280 + i], pv, p1);
            }
            red[tid] = p0; red[256 + tid] = p1;
        }
        __syncthreads();
        if (tid == 0) {
            float l0 = lin_b[0], l1 = lin_b[1];
            for (int i = 0; i < 256; ++i) { l0 += red[i]; l1 += red[256 + i]; }
            float m2 = fmaxf(l0, l1);
            float e0 = __expf(l0 - m2), e1 = __expf(l1 - m2);
            float s = e0 + e1;
            out[b * 2 + 0] = e0 / s;
            out[b * 2 + 1] = e1 / s;
        }
    }
}

// ---------------------------------------------------------------------------
extern "C" void kernel_launch(void* const* d_in, const int* in_sizes, int n_in,
                              void* d_out, int out_size, void* d_ws, size_t ws_size,
                              hipStream_t stream) {
    const float* x         = (const float*)d_in[0];
    const float* edge_attr = (const float*)d_in[1];
    const int*   ei        = (const int*)d_in[2];
    const float* WA        = (const float*)d_in[3];
    const float* WB        = (const float*)d_in[4];
    const float* gcn_bias  = (const float*)d_in[5];
    const float* w_ih[3] = {(const float*)d_in[6],  (const float*)d_in[10], (const float*)d_in[14]};
    const float* w_hh[3] = {(const float*)d_in[7],  (const float*)d_in[11], (const float*)d_in[15]};
    const float* b_ih[3] = {(const float*)d_in[8],  (const float*)d_in[12], (const float*)d_in[16]};
    const float* b_hh[3] = {(const float*)d_in[9],  (const float*)d_in[13], (const float*)d_in[17]};
    const float* lin_W = (const float*)d_in[18];
    const float* lin_b = (const float*)d_in[19];
    float* out = (float*)d_out;

    char* p = (char*)d_ws;
    auto alloc = [&](size_t bytes) {
        char* r = p;
        p += (bytes + 255) & ~(size_t)255;
        return r;
    };
    int*   deg    = (int*)alloc((size_t)NN * 4);   // ┐ contiguous: one memset
    int*   offs   = (int*)alloc((size_t)NN * 4);   // │
    int*   cursor = (int*)alloc((size_t)NN * 4);   // ┘
    float* dinv   = (float*)alloc((size_t)NN * 4);
    int*   eidx   = (int*)alloc((size_t)NE * 4);
    float* Bself  = (float*)alloc(256 * 4);
    float* hT     = (float*)alloc(2 * NB * 256 * 4);
    float* bias768 = (float*)alloc(3 * G3 * 4);
    float* Ax     = (float*)alloc((size_t)NN * DOUT * 4);
    _Float16* xp16 = (_Float16*)alloc((size_t)NN * G3 * 2);

    _Float16* node16 = (_Float16*)alloc((size_t)NN * DOUT * 2);
    _Float16* yA16   = (_Float16*)alloc((size_t)NN * DOUT * 2);
    _Float16* x16    = (_Float16*)alloc((size_t)NN * DOUT * 2);
    _Float16* yB16   = x16;  // alias: x16 dead after Ax GEMM, yB16 live later
    _Float16* WA16   = (_Float16*)alloc((size_t)256 * 256 * 2);
    _Float16* wih16[3];
    for (int l = 0; l < 3; ++l) wih16[l] = (_Float16*)alloc((size_t)G3 * 256 * 2);

    // --- CSR build + weight conversions + bias fold ---
    hipMemsetAsync(deg, 0, (size_t)3 * NN * 4, stream);    // deg+offs+cursor
    k_count<<<NE / 256, 256, 0, stream>>>(ei, deg);
    k_scan_offs<<<1, 1024, 0, stream>>>(deg, offs, dinv);
    k_fill<<<NE / 256, 256, 0, stream>>>(ei, offs, cursor, eidx);
    k_bself<<<1, 256, 0, stream>>>(WB, Bself);
    k_bias_fold<<<9, 256, 0, stream>>>(b_ih[0], b_hh[0], b_ih[1], b_hh[1],
                                       b_ih[2], b_hh[2], bias768);
    k_cvt_all<<<4736, 256, 0, stream>>>(x, WA, w_ih[0], w_ih[1], w_ih[2],
                                        x16, WA16, wih16[0], wih16[1], wih16[2]);

    // --- GCN ---
    {
        dim3 g(NN / 128, 256 / 128);
        k_gemm16<false><<<g, 256, 0, stream>>>(x16, WA16, nullptr, Ax, NN, 256);
    }
    k_gcn<<<NN, 256, 0, stream>>>(Ax, WB, edge_attr, ei, eidx, offs, deg, dinv,
                                  Bself, gcn_bias, node16);

    // --- GRU x3 (layer 2 fuses pooling+linear+softmax) ---
    const _Float16* in16 = node16;
    _Float16* y16_outs[3] = {yA16, yB16, yA16};
    for (int l = 0; l < 3; ++l) {
        dim3 g(NN / 128, G3 / 128);
        k_gemm16<true><<<g, 256, 0, stream>>>(in16, wih16[l], bias768 + l * G3,
                                              xp16, NN, G3);
        k_gru_scan<<<NB, 512, 0, stream>>>(xp16, w_hh[l], b_hh[l], y16_outs[l],
                                           hT, l, lin_W, lin_b, out);
        in16 = y16_outs[l];
    }
}